// Round 3
// baseline (154.241 us; speedup 1.0000x reference)
//
#include <hip/hip_runtime.h>
#include <math.h>

#define BB 64
#define NN 512
#define FF 128

typedef __bf16 bf16x8 __attribute__((ext_vector_type(8)));
typedef float floatx4 __attribute__((ext_vector_type(4)));

// round-to-nearest-even f32 -> bf16 bits
__device__ __forceinline__ unsigned int bf16u(float f) {
    unsigned int u = __builtin_bit_cast(unsigned int, f);
    unsigned int r = (u + 0x7FFFu + ((u >> 16) & 1u)) >> 16;
    return r & 0xFFFFu;
}

// ---------------- Kernel 1: row softmax of weight [N,N] -> S ----------------
__global__ __launch_bounds__(256) void softmax_kernel(const float* __restrict__ w,
                                                      float* __restrict__ S) {
    const int row = blockIdx.x;
    const float* wr = w + (size_t)row * NN;
    float* sr = S + (size_t)row * NN;
    const int tid = threadIdx.x;
    const int wave = tid >> 6, lane = tid & 63;

    float v0 = wr[tid];
    float v1 = wr[tid + 256];

    float m = fmaxf(v0, v1);
    #pragma unroll
    for (int off = 32; off > 0; off >>= 1)
        m = fmaxf(m, __shfl_down(m, off, 64));
    __shared__ float red[8];
    if (lane == 0) red[wave] = m;
    __syncthreads();
    if (tid == 0) red[4] = fmaxf(fmaxf(red[0], red[1]), fmaxf(red[2], red[3]));
    __syncthreads();
    m = red[4];

    float e0 = expf(v0 - m);
    float e1 = expf(v1 - m);

    float s = e0 + e1;
    #pragma unroll
    for (int off = 32; off > 0; off >>= 1)
        s += __shfl_down(s, off, 64);
    __syncthreads();
    if (lane == 0) red[wave] = s;
    __syncthreads();
    if (tid == 0) red[5] = 1.0f / (red[0] + red[1] + red[2] + red[3]);
    __syncthreads();
    const float inv = red[5];

    sr[tid]       = e0 * inv;
    sr[tid + 256] = e1 * inv;
}

// ---- Kernel 2 (v2): d[b,i] = rsqrt(1 + sum_j S[i,j]*mask[b,i,j]) ----------
// block = (b, group of 16 rows); 16 threads per row, 8 float4 each.
__global__ __launch_bounds__(256) void rowsum_kernel(const float* __restrict__ S,
                                                     const float* __restrict__ mask,
                                                     float* __restrict__ dvec) {
    const int b = blockIdx.x >> 5;
    const int g = blockIdx.x & 31;
    const int r = threadIdx.x >> 4;
    const int l = threadIdx.x & 15;
    const int i = g * 16 + r;

    const float4* mrow = (const float4*)(mask + ((size_t)b * NN + i) * NN);
    const float4* srow = (const float4*)(S + (size_t)i * NN);

    float sum = 0.f;
    #pragma unroll
    for (int k = 0; k < 8; ++k) {
        float4 mv = mrow[l + 16 * k];
        float4 sv = srow[l + 16 * k];
        sum += mv.x * sv.x + mv.y * sv.y + mv.z * sv.z + mv.w * sv.w;
    }
    #pragma unroll
    for (int off = 8; off > 0; off >>= 1)
        sum += __shfl_down(sum, off, 16);
    if (l == 0) {
        float rs = sum + 1.0f;
        dvec[b * NN + i] = (rs > 0.f) ? (1.0f / sqrtf(rs)) : 0.f;
    }
}

// ---- Kernel 3: Xt[b][f][j] = bf16(d_j * x[b][j][f])  (per-batch transpose) -
#define PADT 129
__global__ __launch_bounds__(256) void xt_kernel(const float* __restrict__ in,
                                                 const float* __restrict__ dvec,
                                                 unsigned short* __restrict__ Xt) {
    __shared__ unsigned short T[64 * PADT];   // [j_local][f], padded
    const int b = blockIdx.y;
    const int j0 = blockIdx.x * 64;
    const int tid = threadIdx.x;

    // phase 1: read x[j][f] coalesced, scale by d_j, scatter bf16 into T[j][f]
    const int fg = tid & 31;   // float4 index along f
    const int jr = tid >> 5;   // 8 j-rows per pass
    #pragma unroll
    for (int p = 0; p < 8; ++p) {
        int j = jr + 8 * p;
        float dj = dvec[b * NN + j0 + j];
        float4 xv = *(const float4*)(in + ((size_t)b * NN + j0 + j) * FF + 4 * fg);
        T[j * PADT + 4 * fg + 0] = (unsigned short)bf16u(xv.x * dj);
        T[j * PADT + 4 * fg + 1] = (unsigned short)bf16u(xv.y * dj);
        T[j * PADT + 4 * fg + 2] = (unsigned short)bf16u(xv.z * dj);
        T[j * PADT + 4 * fg + 3] = (unsigned short)bf16u(xv.w * dj);
    }
    __syncthreads();

    // phase 2: gather 8 j's per fixed f, write 16B chunks of Xt row f
    const int c = tid & 7;     // 8-j chunk
    const int fr = tid >> 3;   // 32 f per pass
    #pragma unroll
    for (int q = 0; q < 4; ++q) {
        int f = fr + 32 * q;
        unsigned int v01 = (unsigned int)T[(8 * c + 0) * PADT + f] |
                           ((unsigned int)T[(8 * c + 1) * PADT + f] << 16);
        unsigned int v23 = (unsigned int)T[(8 * c + 2) * PADT + f] |
                           ((unsigned int)T[(8 * c + 3) * PADT + f] << 16);
        unsigned int v45 = (unsigned int)T[(8 * c + 4) * PADT + f] |
                           ((unsigned int)T[(8 * c + 5) * PADT + f] << 16);
        unsigned int v67 = (unsigned int)T[(8 * c + 6) * PADT + f] |
                           ((unsigned int)T[(8 * c + 7) * PADT + f] << 16);
        uint4 pk = make_uint4(v01, v23, v45, v67);
        *(uint4*)(Xt + ((size_t)b * FF + f) * NN + j0 + 8 * c) = pk;
    }
}

// ---- Kernel 4: MFMA matmul, A double-buffered in LDS, B from global Xt -----
#define TI 32
#define ASTR 72   // bf16 elems; 144 B rows (16B-aligned), 2-way banks = free
__global__ __launch_bounds__(256) void matmul_kernel(const float* __restrict__ S,
                                                     const float* __restrict__ mask,
                                                     const float* __restrict__ dvec,
                                                     const unsigned short* __restrict__ Xt,
                                                     const float* __restrict__ in,
                                                     float* __restrict__ out) {
    __shared__ __align__(16) unsigned short Alds[2][TI * ASTR];

    const int b = blockIdx.y;
    const int i_base = blockIdx.x * TI;
    const int tid = threadIdx.x;
    const int w = tid >> 6;
    const int lane = tid & 63;
    const int quad = lane >> 4;
    const int l16 = lane & 15;
    const int iw = (w & 1) * 16;
    const int fw = (w >> 1) * 64;

    const float* dB = dvec + b * NN;
    const unsigned short* XtB = Xt + (size_t)b * FF * NN;

    floatx4 acc[4];
    #pragma unroll
    for (int nt = 0; nt < 4; nt++) acc[nt] = (floatx4){0.f, 0.f, 0.f, 0.f};

    const int a_il = tid >> 3;          // 0..31 row
    const int a_js = (tid & 7) * 8;     // j offset 0..56
    const float* mbase = mask + ((size_t)b * NN + i_base + a_il) * NN + a_js;
    const float* sbase = S + (size_t)(i_base + a_il) * NN + a_js;
    unsigned short* awr = &Alds[0][0] + a_il * ASTR + a_js;

    // prologue: stage chunk 0 into buffer 0
    {
        float4 m0 = *(const float4*)(mbase);
        float4 m1 = *(const float4*)(mbase + 4);
        float4 s0 = *(const float4*)(sbase);
        float4 s1 = *(const float4*)(sbase + 4);
        uint4 pk;
        pk.x = bf16u(m0.x * s0.x) | (bf16u(m0.y * s0.y) << 16);
        pk.y = bf16u(m0.z * s0.z) | (bf16u(m0.w * s0.w) << 16);
        pk.z = bf16u(m1.x * s1.x) | (bf16u(m1.y * s1.y) << 16);
        pk.w = bf16u(m1.z * s1.z) | (bf16u(m1.w * s1.w) << 16);
        *(uint4*)awr = pk;
    }

    #pragma unroll
    for (int c = 0; c < 8; ++c) {
        const int p = c & 1;
        // issue next chunk's global loads early (long latency, no LDS dep)
        float4 m0, m1, s0, s1;
        if (c < 7) {
            int jn = (c + 1) * 64;
            m0 = *(const float4*)(mbase + jn);
            m1 = *(const float4*)(mbase + jn + 4);
            s0 = *(const float4*)(sbase + jn);
            s1 = *(const float4*)(sbase + jn + 4);
        }
        __syncthreads();   // buf[p] writes visible; prior reads of buf[p^1] done

        const int j0 = c * 64;
        // load all B-frags (global, L2-warm), then A-frags, then MFMA
        bf16x8 bfr[2][4];
        #pragma unroll
        for (int s = 0; s < 2; ++s)
            #pragma unroll
            for (int nt = 0; nt < 4; ++nt)
                bfr[s][nt] = *(const bf16x8*)&XtB[(size_t)(fw + nt * 16 + l16) * NN + j0 + s * 32 + quad * 8];
        #pragma unroll
        for (int s = 0; s < 2; ++s) {
            bf16x8 af = *(const bf16x8*)&Alds[p][(iw + l16) * ASTR + s * 32 + quad * 8];
            #pragma unroll
            for (int nt = 0; nt < 4; ++nt)
                acc[nt] = __builtin_amdgcn_mfma_f32_16x16x32_bf16(af, bfr[s][nt], acc[nt], 0, 0, 0);
        }

        if (c < 7) {
            uint4 pk;
            pk.x = bf16u(m0.x * s0.x) | (bf16u(m0.y * s0.y) << 16);
            pk.y = bf16u(m0.z * s0.z) | (bf16u(m0.w * s0.w) << 16);
            pk.z = bf16u(m1.x * s1.x) | (bf16u(m1.y * s1.y) << 16);
            pk.w = bf16u(m1.z * s1.z) | (bf16u(m1.w * s1.w) << 16);
            *(uint4*)(&Alds[p ^ 1][0] + a_il * ASTR + a_js) = pk;
        }
    }

    // epilogue: out = d_i * (acc + d_i * x_i), identity term in fp32
    #pragma unroll
    for (int nt = 0; nt < 4; nt++) {
        int f = fw + nt * 16 + l16;
        #pragma unroll
        for (int r = 0; r < 4; r++) {
            int i = i_base + iw + quad * 4 + r;
            float di = dB[i];
            float x = in[((size_t)b * NN + i) * FF + f];
            out[((size_t)b * NN + i) * FF + f] = di * (acc[nt][r] + di * x);
        }
    }
}

extern "C" void kernel_launch(void* const* d_in, const int* in_sizes, int n_in,
                              void* d_out, int out_size, void* d_ws, size_t ws_size,
                              hipStream_t stream) {
    const float* inp  = (const float*)d_in[0];   // [B,N,F]
    const float* mask = (const float*)d_in[1];   // [B,N,N]
    const float* w    = (const float*)d_in[2];   // [N,N]
    float* out = (float*)d_out;                  // [B,N,F]

    unsigned short* Xt = (unsigned short*)d_ws;              // B*F*N bf16 = 8 MB
    float* S    = (float*)(Xt + (size_t)BB * FF * NN);       // N*N f32 = 1 MB
    float* dvec = S + (size_t)NN * NN;                       // B*N f32

    softmax_kernel<<<NN, 256, 0, stream>>>(w, S);
    rowsum_kernel<<<BB * 32, 256, 0, stream>>>(S, mask, dvec);
    dim3 gx(NN / 64, BB);
    xt_kernel<<<gx, 256, 0, stream>>>(inp, dvec, Xt);
    dim3 g3(NN / TI, BB);
    matmul_kernel<<<g3, 256, 0, stream>>>(S, mask, dvec, Xt, inp, out);
}

// Round 5
// 147.296 us; speedup vs baseline: 1.0471x; 1.0471x over previous
//
#include <hip/hip_runtime.h>
#include <math.h>

#define BB 64
#define NN 512
#define FF 128
#define ASTR 72    // bf16 elems per A-row in LDS (144 B, 16B-aligned)
#define PADT 129   // transpose buffer pad
#define TI2 16     // matmul i-tile

typedef __bf16 bf16x8 __attribute__((ext_vector_type(8)));
typedef float floatx4 __attribute__((ext_vector_type(4)));

// round-to-nearest-even f32 -> bf16 bits
__device__ __forceinline__ unsigned int bf16u(float f) {
    unsigned int u = __builtin_bit_cast(unsigned int, f);
    unsigned int r = (u + 0x7FFFu + ((u >> 16) & 1u)) >> 16;
    return r & 0xFFFFu;
}

// ---- Kernel 1: fused row-softmax(w) -> S  AND  dvec[b,i] for 16 batches ----
// grid (NN, 4): block = (row i, batch-group bg). Softmax recomputed per bg
// (cheap, w row L2-hot); only bg==0 writes S. Then each of 4 waves handles
// 4 batches: dvec[b,i] = rsqrt(1 + sum_j S[i,j]*mask[b,i,j]).
__global__ __launch_bounds__(256) void softmax_rowsum_kernel(
        const float* __restrict__ w, const float* __restrict__ mask,
        float* __restrict__ S, float* __restrict__ dvec) {
    __shared__ float Srow[NN];
    __shared__ float red[8];
    const int row = blockIdx.x;
    const int bg = blockIdx.y;
    const int tid = threadIdx.x;
    const int wv = tid >> 6, lane = tid & 63;

    float v0 = w[(size_t)row * NN + tid];
    float v1 = w[(size_t)row * NN + tid + 256];

    float m = fmaxf(v0, v1);
    #pragma unroll
    for (int off = 32; off > 0; off >>= 1)
        m = fmaxf(m, __shfl_down(m, off, 64));
    if (lane == 0) red[wv] = m;
    __syncthreads();
    if (tid == 0) red[4] = fmaxf(fmaxf(red[0], red[1]), fmaxf(red[2], red[3]));
    __syncthreads();
    m = red[4];

    float e0 = expf(v0 - m);
    float e1 = expf(v1 - m);
    float s = e0 + e1;
    #pragma unroll
    for (int off = 32; off > 0; off >>= 1)
        s += __shfl_down(s, off, 64);
    __syncthreads();
    if (lane == 0) red[wv] = s;
    __syncthreads();
    if (tid == 0) red[5] = 1.0f / (red[0] + red[1] + red[2] + red[3]);
    __syncthreads();
    const float inv = red[5];
    const float s0v = e0 * inv, s1v = e1 * inv;

    Srow[tid] = s0v;
    Srow[tid + 256] = s1v;
    if (bg == 0) {
        S[(size_t)row * NN + tid] = s0v;
        S[(size_t)row * NN + tid + 256] = s1v;
    }
    __syncthreads();

    // lane covers j = lane*8 .. lane*8+7
    float4 sA = *(const float4*)&Srow[lane * 8];
    float4 sB = *(const float4*)&Srow[lane * 8 + 4];

    // 4 batches per wave; load all mask data first (16 loads in flight)
    float4 mA[4], mB[4];
    #pragma unroll
    for (int t = 0; t < 4; ++t) {
        int b = bg * 16 + wv * 4 + t;
        const float4* mrow = (const float4*)(mask + ((size_t)b * NN + row) * NN);
        mA[t] = mrow[2 * lane];
        mB[t] = mrow[2 * lane + 1];
    }
    #pragma unroll
    for (int t = 0; t < 4; ++t) {
        float sum = mA[t].x * sA.x + mA[t].y * sA.y + mA[t].z * sA.z + mA[t].w * sA.w
                  + mB[t].x * sB.x + mB[t].y * sB.y + mB[t].z * sB.z + mB[t].w * sB.w;
        #pragma unroll
        for (int off = 32; off > 0; off >>= 1)
            sum += __shfl_down(sum, off, 64);
        if (lane == 0) {
            int b = bg * 16 + wv * 4 + t;
            float rs = sum + 1.0f;
            dvec[b * NN + row] = (rs > 0.f) ? (1.0f / sqrtf(rs)) : 0.f;
        }
    }
}

// ---- Kernel 2: Xt[b][f][j] = bf16(d_j * x[b][j][f])  (per-batch transpose) -
__global__ __launch_bounds__(256) void xt_kernel(const float* __restrict__ in,
                                                 const float* __restrict__ dvec,
                                                 unsigned short* __restrict__ Xt) {
    __shared__ unsigned short T[64 * PADT];
    const int b = blockIdx.y;
    const int j0 = blockIdx.x * 64;
    const int tid = threadIdx.x;

    const int fg = tid & 31;
    const int jr = tid >> 5;
    #pragma unroll
    for (int p = 0; p < 8; ++p) {
        int j = jr + 8 * p;
        float dj = dvec[b * NN + j0 + j];
        float4 xv = *(const float4*)(in + ((size_t)b * NN + j0 + j) * FF + 4 * fg);
        T[j * PADT + 4 * fg + 0] = (unsigned short)bf16u(xv.x * dj);
        T[j * PADT + 4 * fg + 1] = (unsigned short)bf16u(xv.y * dj);
        T[j * PADT + 4 * fg + 2] = (unsigned short)bf16u(xv.z * dj);
        T[j * PADT + 4 * fg + 3] = (unsigned short)bf16u(xv.w * dj);
    }
    __syncthreads();
    const int c = tid & 7;
    const int fr = tid >> 3;
    #pragma unroll
    for (int q = 0; q < 4; ++q) {
        int f = fr + 32 * q;
        unsigned int v01 = (unsigned int)T[(8 * c + 0) * PADT + f] |
                           ((unsigned int)T[(8 * c + 1) * PADT + f] << 16);
        unsigned int v23 = (unsigned int)T[(8 * c + 2) * PADT + f] |
                           ((unsigned int)T[(8 * c + 3) * PADT + f] << 16);
        unsigned int v45 = (unsigned int)T[(8 * c + 4) * PADT + f] |
                           ((unsigned int)T[(8 * c + 5) * PADT + f] << 16);
        unsigned int v67 = (unsigned int)T[(8 * c + 6) * PADT + f] |
                           ((unsigned int)T[(8 * c + 7) * PADT + f] << 16);
        *(uint4*)(Xt + ((size_t)b * FF + f) * NN + j0 + 8 * c) = make_uint4(v01, v23, v45, v67);
    }
}

// ---- Kernel 3: MFMA matmul, TI=16, grid (32,64)=2048 blocks ----------------
// wave wv: all 16 rows, f-slice fw = wv*32 (2 n-tiles). A double-buffered in
// LDS; B-frags prefetched from global Xt (L2-resident).
__global__ __launch_bounds__(256) void matmul_kernel(
        const float* __restrict__ S, const float* __restrict__ mask,
        const float* __restrict__ dvec, const unsigned short* __restrict__ Xt,
        const float* __restrict__ in, float* __restrict__ out) {
    __shared__ __align__(16) unsigned short Alds[2][TI2 * ASTR];

    const int b = blockIdx.y;
    const int i_base = blockIdx.x * TI2;
    const int tid = threadIdx.x;
    const int wv = tid >> 6;
    const int lane = tid & 63;
    const int quad = lane >> 4;
    const int l16 = lane & 15;
    const int fw = wv * 32;

    const float* dB = dvec + b * NN;
    const unsigned short* XtB = Xt + (size_t)b * FF * NN;

    floatx4 acc[2];
    acc[0] = (floatx4){0.f, 0.f, 0.f, 0.f};
    acc[1] = (floatx4){0.f, 0.f, 0.f, 0.f};

    // A staging: thread t -> row t>>4 (0..15), j-offset (t&15)*4
    const int a_il = tid >> 4;
    const int a_js = (tid & 15) * 4;
    const float* mbase = mask + ((size_t)b * NN + i_base + a_il) * NN + a_js;
    const float* sbase = S + (size_t)(i_base + a_il) * NN + a_js;

    // prologue: stage chunk 0 into buffer 0
    {
        float4 m0 = *(const float4*)mbase;
        float4 s0 = *(const float4*)sbase;
        uint2 pk;
        pk.x = bf16u(m0.x * s0.x) | (bf16u(m0.y * s0.y) << 16);
        pk.y = bf16u(m0.z * s0.z) | (bf16u(m0.w * s0.w) << 16);
        *(uint2*)(&Alds[0][0] + a_il * ASTR + a_js) = pk;
    }
    // prefetch B-frags for chunk 0: [s][nt]
    bf16x8 bcur[4];
    #pragma unroll
    for (int s = 0; s < 2; ++s)
        #pragma unroll
        for (int nt = 0; nt < 2; ++nt)
            bcur[s * 2 + nt] = *(const bf16x8*)&XtB[(size_t)(fw + nt * 16 + l16) * NN + s * 32 + quad * 8];

    #pragma unroll
    for (int c = 0; c < 8; ++c) {
        const int p = c & 1;
        float4 m0, s0;
        if (c < 7) {
            m0 = *(const float4*)(mbase + (c + 1) * 64);
            s0 = *(const float4*)(sbase + (c + 1) * 64);
        }
        __syncthreads();   // Alds[p] writes visible; prior reads of Alds[p^1] done

        bf16x8 bnxt[4];
        if (c < 7) {
            int jn = (c + 1) * 64;
            #pragma unroll
            for (int s = 0; s < 2; ++s)
                #pragma unroll
                for (int nt = 0; nt < 2; ++nt)
                    bnxt[s * 2 + nt] = *(const bf16x8*)&XtB[(size_t)(fw + nt * 16 + l16) * NN + jn + s * 32 + quad * 8];
        }

        #pragma unroll
        for (int s = 0; s < 2; ++s) {
            bf16x8 af = *(const bf16x8*)&Alds[p][l16 * ASTR + s * 32 + quad * 8];
            #pragma unroll
            for (int nt = 0; nt < 2; ++nt)
                acc[nt] = __builtin_amdgcn_mfma_f32_16x16x32_bf16(af, bcur[s * 2 + nt], acc[nt], 0, 0, 0);
        }

        if (c < 7) {
            uint2 pk;
            pk.x = bf16u(m0.x * s0.x) | (bf16u(m0.y * s0.y) << 16);
            pk.y = bf16u(m0.z * s0.z) | (bf16u(m0.w * s0.w) << 16);
            *(uint2*)(&Alds[p ^ 1][0] + a_il * ASTR + a_js) = pk;
            #pragma unroll
            for (int q = 0; q < 4; ++q) bcur[q] = bnxt[q];
        }
    }

    // epilogue: out = d_i * (acc + d_i * x_i), identity term in fp32
    #pragma unroll
    for (int nt = 0; nt < 2; ++nt) {
        int f = fw + nt * 16 + l16;
        #pragma unroll
        for (int r = 0; r < 4; ++r) {
            int i = i_base + quad * 4 + r;
            float di = dB[i];
            float x = in[((size_t)b * NN + i) * FF + f];
            out[((size_t)b * NN + i) * FF + f] = di * (acc[nt][r] + di * x);
        }
    }
}

extern "C" void kernel_launch(void* const* d_in, const int* in_sizes, int n_in,
                              void* d_out, int out_size, void* d_ws, size_t ws_size,
                              hipStream_t stream) {
    const float* inp  = (const float*)d_in[0];   // [B,N,F]
    const float* mask = (const float*)d_in[1];   // [B,N,N]
    const float* w    = (const float*)d_in[2];   // [N,N]
    float* out = (float*)d_out;                  // [B,N,F]

    unsigned short* Xt = (unsigned short*)d_ws;              // B*F*N bf16 = 8 MB
    float* S    = (float*)(Xt + (size_t)BB * FF * NN);       // N*N f32 = 1 MB
    float* dvec = S + (size_t)NN * NN;                       // B*N f32

    softmax_rowsum_kernel<<<dim3(NN, 4), 256, 0, stream>>>(w, mask, S, dvec);
    xt_kernel<<<dim3(NN / 64, BB), 256, 0, stream>>>(inp, dvec, Xt);
    matmul_kernel<<<dim3(NN / TI2, BB), 256, 0, stream>>>(S, mask, dvec, Xt, inp, out);
}